// Round 15
// baseline (38.889 us; speedup 1.0000x reference)
//
#include <hip/hip_runtime.h>

#define NUM_NODES 16384
#define NPG 8
#define NUM_EDGES 14336
#define EPG 7
#define NUM_RELS 64
#define DIM 128
#define BATCH 2048
#define EPS 1e-8f

#define SEG 1792                     // NUM_EDGES / 8 segments
#define EDGE_BLOCKS 512              // bid 0..511: 64 rel x 8 segments (dispatched FIRST -> deadlock-free)
#define ROOT_BLOCKS 256              // bid 512..767: 64 rows each + per-graph finalize
#define READY 0x5A5A5A5A             // != 0xAAAAAAAA poison, != 0 reset

using f16x2 = __attribute__((ext_vector_type(2))) _Float16;
using f16x8 = __attribute__((ext_vector_type(8))) _Float16;
using f32x4 = __attribute__((ext_vector_type(4))) float;

// ---- ws layout (bytes) ----
#define FLG_OFF 0u                   // flags: 14336*4 = 57344 (reader-reset -> replay-safe)
#define MSG_OFF 57344u               // msg_h: 14336*128*2 = 3670016
#define DUM_OFF 3727360u             // dummy publish/acquire target
#define WS_NEEDED 3727616u

// ---------------- THE single kernel ----------------
// Edge block: bucket own 1792-edge segment (LDS-atomic slot grab), pack B[rel]
// fp32->f16 transposed+swizzled into LDS, 64-row MFMA strip -> msg_h; then
// publish: syncthreads (vmcnt drain) -> thread0 RELEASE fetch_add (XCD-L2
// writeback, R10-validated) -> per-edge flag atomic-exchange READY.
// Root block: pack root, MFMA for rows rb*64.., C-tile -> LDS (stride 132,
// conflict-free); wave0 polls its 56 contiguous edge flags RELAXED, resets
// them to 0 (next-replay init), one ACQUIRE; finalize 8 graphs in-block.
__global__ __launch_bounds__(256, 4) void rgcn_one_kernel(
    const float* __restrict__ x, const float* __restrict__ basis,
    const float* __restrict__ root, const float* __restrict__ bias,
    const float* __restrict__ target, const int* __restrict__ edge_index,
    const int* __restrict__ edge_type, float* __restrict__ out,
    int* __restrict__ flags, _Float16* __restrict__ msg_h, int* __restrict__ dummy)
{
    __shared__ _Float16 Bl[DIM * DIM];   // 32 KB; root blocks reuse as C-tile after MFMA
    __shared__ int smeta[128];           // [0:64) src node, [64:128) out row id (-1 = skip)
    __shared__ int lcnt;

    const int bid = blockIdx.x;
    const int tid = threadIdx.x;
    const int lane = tid & 63;
    const int w    = tid >> 6;
    const bool isEdge = bid < EDGE_BLOCKS;

    const float* Bsrc;

    // ---- init metadata ----
    if (isEdge) {
        if (tid < 64) { smeta[tid] = 0; smeta[64 + tid] = -1; }
        if (tid == 0) lcnt = 0;
        Bsrc = basis + ((size_t)(bid >> 3) << 14);
    } else {
        const int row0 = (bid - EDGE_BLOCKS) * 64;
        if (tid < 64) {
            smeta[tid] = row0 + tid;
            smeta[64 + tid] = row0 + tid;
        }
        Bsrc = root;
    }
    __syncthreads();

    // ---- scan (edge blocks; no barriers, interleaves with pack) ----
    if (isEdge) {
        const int rel  = bid >> 3;
        const int seg0 = (bid & 7) * SEG;
        #pragma unroll
        for (int it = 0; it < 7; ++it) {
            const int e = seg0 + it * 256 + tid;
            if (edge_type[e] == rel) {
                const int pos = atomicAdd(&lcnt, 1);
                if (pos < 64) {
                    smeta[pos] = edge_index[e];
                    smeta[64 + pos] = e;
                }
            }
        }
    }

    // ---- pack B: fp32 [d][o] -> LDS f16 [col][k], 8x8 in-register transpose ----
    {
        const int br = tid >> 4;         // d-block
        const int bc = tid & 15;         // o-block
        const float* src = Bsrc + (br * 8) * DIM + bc * 8;
        _Float16 m[8][8];
        #pragma unroll
        for (int u = 0; u < 8; ++u) {
            const float4 a = *(const float4*)(src + u * DIM);
            const float4 b = *(const float4*)(src + u * DIM + 4);
            m[u][0] = (_Float16)a.x; m[u][1] = (_Float16)a.y;
            m[u][2] = (_Float16)a.z; m[u][3] = (_Float16)a.w;
            m[u][4] = (_Float16)b.x; m[u][5] = (_Float16)b.y;
            m[u][6] = (_Float16)b.z; m[u][7] = (_Float16)b.w;
        }
        #pragma unroll
        for (int c2 = 0; c2 < 8; ++c2) {
            const int chunk = (bc * 8 + c2) * 16 + br;
            const int cs = chunk ^ (c2 & 7) ^ (bc & 7);
            f16x8 v = {m[0][c2], m[1][c2], m[2][c2], m[3][c2],
                       m[4][c2], m[5][c2], m[6][c2], m[7][c2]};
            *(f16x8*)(&Bl[cs * 8]) = v;
        }
    }
    __syncthreads();

    if (isEdge && lcnt == 0) return;     // block-uniform; owes no flags

    const int l15 = lane & 15;
    const int q   = lane >> 4;

    // ---- A fragments: gather fp32 x row, cvt in-register ----
    const int srcn = smeta[w * 16 + l15];
    const float* xrow = x + ((size_t)srcn << 7) + q * 8;
    f16x8 a[4];
    #pragma unroll
    for (int kb = 0; kb < 4; ++kb) {
        const float4 lo = *(const float4*)(xrow + kb * 32);
        const float4 hi = *(const float4*)(xrow + kb * 32 + 4);
        f16x8 av;
        av[0] = (_Float16)lo.x; av[1] = (_Float16)lo.y;
        av[2] = (_Float16)lo.z; av[3] = (_Float16)lo.w;
        av[4] = (_Float16)hi.x; av[5] = (_Float16)hi.y;
        av[6] = (_Float16)hi.z; av[7] = (_Float16)hi.w;
        a[kb] = av;
    }

    f32x4 acc[8];
    #pragma unroll
    for (int ct = 0; ct < 8; ++ct) acc[ct] = (f32x4){0.f, 0.f, 0.f, 0.f};

    #pragma unroll
    for (int ct = 0; ct < 8; ++ct) {
        const int col = ct * 16 + l15;
        const int sw  = (col & 7) ^ ((col >> 3) & 7);
        #pragma unroll
        for (int kb = 0; kb < 4; ++kb) {
            const int chunk = col * 16 + kb * 4 + q;
            const f16x8 bfr = *(const f16x8*)(&Bl[(chunk ^ sw) * 8]);
            acc[ct] = __builtin_amdgcn_mfma_f32_16x16x32_f16(a[kb], bfr, acc[ct], 0, 0, 0);
        }
    }

    if (isEdge) {
        // ---- msg stores + publish + flags ----
        #pragma unroll
        for (int j = 0; j < 4; ++j) {
            const int r = w * 16 + q * 4 + j;
            const int oid = smeta[64 + r];
            if (oid >= 0) {
                #pragma unroll
                for (int ct = 0; ct < 8; ++ct)
                    msg_h[((size_t)oid << 7) + ct * 16 + l15] = (_Float16)acc[ct][j];
            }
        }
        __syncthreads();                 // vmcnt(0): all msg stores complete at L2
        if (tid == 0)                    // RELEASE publish: XCD-L2 writeback (R10-validated)
            __hip_atomic_fetch_add(dummy, 1, __ATOMIC_RELEASE, __HIP_MEMORY_SCOPE_AGENT);
        __syncthreads();                 // publish done before any flag is set
        if (tid < 64) {
            const int oid = smeta[64 + tid];
            if (oid >= 0)
                (void)__hip_atomic_exchange(flags + oid, READY,
                                            __ATOMIC_RELAXED, __HIP_MEMORY_SCOPE_AGENT);
        }
        return;
    }

    // ================= root block: C -> LDS, poll, finalize =================
    __syncthreads();                     // all B-fragment reads done before Bl reuse
    _Float16* Cl = Bl;                   // [64][132] f16 = 16.9 KB (stride 132: conflict-free)
    #pragma unroll
    for (int j = 0; j < 4; ++j) {
        const int lr = w * 16 + q * 4 + j;
        #pragma unroll
        for (int ct = 0; ct < 8; ++ct)
            Cl[lr * 132 + ct * 16 + l15] = (_Float16)acc[ct][j];
    }
    __syncthreads();

    const int rb = bid - EDGE_BLOCKS;
    // poll this block's 56 contiguous edge flags; reset after consumption
    if (w == 0 && lane < 56) {
        int* fp = flags + rb * 56 + lane;
        while (__hip_atomic_load(fp, __ATOMIC_RELAXED, __HIP_MEMORY_SCOPE_AGENT) != READY)
            __builtin_amdgcn_s_sleep(2);
        __hip_atomic_store(fp, 0, __ATOMIC_RELAXED, __HIP_MEMORY_SCOPE_AGENT);
    }
    __syncthreads();
    if (tid == 0)                        // single ACQUIRE invalidates stale cache
        (void)__hip_atomic_load(dummy, __ATOMIC_ACQUIRE, __HIP_MEMORY_SCOPE_AGENT);
    __syncthreads();

    // finalize: wave w handles graphs rb*8 + w*2 + {0,1}
    #pragma unroll
    for (int k = 0; k < 2; ++k) {
        const int lg = w * 2 + k;
        const int g  = rb * 8 + lg;
        const int d0 = lane * 2;

        const float2 bv = *(const float2*)(bias + d0);
        float accA[NPG], accB[NPG];
        #pragma unroll
        for (int n = 0; n < NPG; ++n) {
            const f16x2 c = *(const f16x2*)(&Cl[(lg * 8 + n) * 132 + d0]);
            accA[n] = bv.x + (float)c[0];
            accB[n] = bv.y + (float)c[1];
        }

        const int ebase = g * EPG;
        #pragma unroll
        for (int e = 0; e < EPG; ++e) {
            const int ge  = ebase + e;
            const int dst = edge_index[NUM_EDGES + ge] - g * NPG;
            const f16x2 mv = *(const f16x2*)(msg_h + ((size_t)ge << 7) + d0);
            const float m0 = (float)mv[0];
            const float m1 = (float)mv[1];
            #pragma unroll
            for (int n = 0; n < NPG; ++n) {
                accA[n] += (n == dst) ? m0 : 0.f;
                accB[n] += (n == dst) ? m1 : 0.f;
            }
        }

        float p0 = 0.f, p1 = 0.f;
        #pragma unroll
        for (int n = 0; n < NPG; ++n) {
            p0 += fmaxf(accA[n], 0.f);
            p1 += fmaxf(accB[n], 0.f);
        }

        const float2 tv = *(const float2*)(target + (size_t)g * DIM + d0);
        float num_p = p0 * tv.x + p1 * tv.y;
        float na_p  = p0 * p0 + p1 * p1;
        float nb_p  = tv.x * tv.x + tv.y * tv.y;

        #pragma unroll
        for (int off = 32; off > 0; off >>= 1) {
            num_p += __shfl_down(num_p, off);
            na_p  += __shfl_down(na_p, off);
            nb_p  += __shfl_down(nb_p, off);
        }
        if (lane == 0) {
            const float na = fmaxf(sqrtf(na_p), EPS);
            const float nb = fmaxf(sqrtf(nb_p), EPS);
            out[g] = num_p / (na * nb);
        }
    }
}

// ---------------- fallback: verified fp32 single-kernel version (52.8 us) ----------------
__global__ __launch_bounds__(128) void rgcn_fused_kernel(
    const float* __restrict__ x, const float* __restrict__ basis,
    const float* __restrict__ root, const float* __restrict__ bias,
    const float* __restrict__ target, const int* __restrict__ edge_index,
    const int* __restrict__ edge_type, float* __restrict__ out)
{
    const int g = blockIdx.x;
    const int o = threadIdx.x;
    __shared__ float xs[NPG][DIM];
    __shared__ float red[6];
    {
        const float4* xg = reinterpret_cast<const float4*>(x + (size_t)g * NPG * DIM);
        float4* xs4 = reinterpret_cast<float4*>(&xs[0][0]);
        xs4[o] = xg[o];
        xs4[o + 128] = xg[o + 128];
    }
    __syncthreads();
    float acc[NPG];
    const float b = bias[o];
    #pragma unroll
    for (int n = 0; n < NPG; ++n) acc[n] = b;
    for (int d4 = 0; d4 < DIM / 4; ++d4) {
        const float r0 = root[(d4 * 4 + 0) * DIM + o];
        const float r1 = root[(d4 * 4 + 1) * DIM + o];
        const float r2 = root[(d4 * 4 + 2) * DIM + o];
        const float r3 = root[(d4 * 4 + 3) * DIM + o];
        #pragma unroll
        for (int n = 0; n < NPG; ++n) {
            const float4 xv = reinterpret_cast<const float4*>(&xs[n][0])[d4];
            acc[n] += xv.x * r0 + xv.y * r1 + xv.z * r2 + xv.w * r3;
        }
    }
    const int ebase = g * EPG;
    for (int e = 0; e < EPG; ++e) {
        const int ge  = ebase + e;
        const int src = edge_index[ge] - g * NPG;
        const int dst = edge_index[NUM_EDGES + ge] - g * NPG;
        const int rel = edge_type[ge];
        const float* __restrict__ B = basis + (size_t)rel * DIM * DIM;
        float m = 0.f;
        for (int d4 = 0; d4 < DIM / 4; ++d4) {
            const float4 xv = reinterpret_cast<const float4*>(&xs[src][0])[d4];
            m += xv.x * B[(d4 * 4 + 0) * DIM + o];
            m += xv.y * B[(d4 * 4 + 1) * DIM + o];
            m += xv.z * B[(d4 * 4 + 2) * DIM + o];
            m += xv.w * B[(d4 * 4 + 3) * DIM + o];
        }
        #pragma unroll
        for (int n = 0; n < NPG; ++n) acc[n] += (n == dst) ? m : 0.f;
    }
    float p = 0.f;
    #pragma unroll
    for (int n = 0; n < NPG; ++n) p += fmaxf(acc[n], 0.f);
    const float t = target[(size_t)g * DIM + o];
    float num_p = p * t, na_p = p * p, nb_p = t * t;
    #pragma unroll
    for (int off = 32; off > 0; off >>= 1) {
        num_p += __shfl_down(num_p, off);
        na_p  += __shfl_down(na_p, off);
        nb_p  += __shfl_down(nb_p, off);
    }
    const int wave = o >> 6, lane = o & 63;
    if (lane == 0) {
        red[wave * 3 + 0] = num_p;
        red[wave * 3 + 1] = na_p;
        red[wave * 3 + 2] = nb_p;
    }
    __syncthreads();
    if (o == 0) {
        const float num = red[0] + red[3];
        const float na  = fmaxf(sqrtf(red[1] + red[4]), EPS);
        const float nb  = fmaxf(sqrtf(red[2] + red[5]), EPS);
        out[g] = num / (na * nb);
    }
}

extern "C" void kernel_launch(void* const* d_in, const int* in_sizes, int n_in,
                              void* d_out, int out_size, void* d_ws, size_t ws_size,
                              hipStream_t stream) {
    const float* x          = (const float*)d_in[0];
    const float* basis      = (const float*)d_in[1];
    const float* root       = (const float*)d_in[2];
    const float* bias       = (const float*)d_in[3];
    const float* target     = (const float*)d_in[4];
    const int*   edge_index = (const int*)d_in[5];
    const int*   edge_type  = (const int*)d_in[6];
    float* out = (float*)d_out;

    if (ws_size < WS_NEEDED) {
        rgcn_fused_kernel<<<BATCH, 128, 0, stream>>>(
            x, basis, root, bias, target, edge_index, edge_type, out);
        return;
    }

    char* ws = (char*)d_ws;
    int*      flags = (int*)(ws + FLG_OFF);
    _Float16* msg_h = (_Float16*)(ws + MSG_OFF);
    int*      dummy = (int*)(ws + DUM_OFF);

    rgcn_one_kernel<<<EDGE_BLOCKS + ROOT_BLOCKS, 256, 0, stream>>>(
        x, basis, root, bias, target, edge_index, edge_type, out,
        flags, msg_h, dummy);
}

// Round 16
// 37.695 us; speedup vs baseline: 1.0317x; 1.0317x over previous
//
#include <hip/hip_runtime.h>

#define NUM_NODES 16384
#define NPG 8
#define NUM_EDGES 14336
#define EPG 7
#define NUM_RELS 64
#define DIM 128
#define BATCH 2048
#define EPS 1e-8f

#define SEG 3584                     // NUM_EDGES / 4 segments
#define ROOT_BLOCKS 64               // bid 0..63: 4 strips x 64 rows each (pack root ONCE per block)
#define EDGE_BLOCKS 256              // bid 64..319: 64 rel x 4 segments; <=128 edges/cell (mean 56, +9.7 sigma)

using f16x2 = __attribute__((ext_vector_type(2))) _Float16;
using f16x8 = __attribute__((ext_vector_type(8))) _Float16;
using f32x4 = __attribute__((ext_vector_type(4))) float;

// ---- ws layout (bytes) ----
#define MSG_OFF 0u                   // msg_h: 14336*128*2 = 3670016
#define RTP_OFF 3670016u             // rootp: 16384*128*2 = 4194304
#define WS_NEEDED 7864320u

// ---------------- kernel 1: fused bucket + pack + MFMA GEMM ----------------
// R14-verified tile math; restructured so each block packs B exactly ONCE:
//  root block (bid<64): 4 strips of 64 rows (256 rows total), one root pack.
//  edge block: rel=(bid-64)>>2, part=(bid-64)&3; buckets its 3584-edge segment
//  via LDS-atomic slot grab (<=128 slots), then 1-2 MFMA strips (2nd only if
//  lcnt>64, P~12%). Packs: 768 -> 320 vs R14; grid 768 -> 320.
// LDS: 16B chunks, chunk = col*16+k16, swizzle cs = chunk^(col&7)^((col>>3)&7)
// -> conflict-free on both transpose stores and fragment reads (R13-verified).
__global__ __launch_bounds__(256, 4) void gemm2_kernel(
    const float* __restrict__ x, const float* __restrict__ basis,
    const float* __restrict__ root, const int* __restrict__ edge_index,
    const int* __restrict__ edge_type,
    _Float16* __restrict__ msg_h, _Float16* __restrict__ rootp_h)
{
    __shared__ _Float16 Bl[DIM * DIM];   // 32 KB
    __shared__ int ssrc[128];            // src node per slot
    __shared__ int soid[128];            // out row id per slot (-1 = skip)
    __shared__ int lcnt;

    const int bid = blockIdx.x;
    const int tid = threadIdx.x;
    const int lane = tid & 63;
    const int w    = tid >> 6;
    const bool isEdge = bid >= ROOT_BLOCKS;

    const float* Bsrc;
    if (isEdge) {
        if (tid < 128) { ssrc[tid] = 0; soid[tid] = -1; }
        if (tid == 0) lcnt = 0;
        Bsrc = basis + ((size_t)((bid - ROOT_BLOCKS) >> 2) << 14);
    } else {
        Bsrc = root;
    }
    __syncthreads();

    // ---- scan (edge blocks; no barriers, interleaves with pack) ----
    if (isEdge) {
        const int eb   = bid - ROOT_BLOCKS;
        const int rel  = eb >> 2;
        const int seg0 = (eb & 3) * SEG;
        #pragma unroll
        for (int it = 0; it < 14; ++it) {
            const int e = seg0 + it * 256 + tid;
            if (edge_type[e] == rel) {
                const int pos = atomicAdd(&lcnt, 1);
                if (pos < 128) {
                    ssrc[pos] = edge_index[e];       // global src node
                    soid[pos] = e;                   // msg row id
                }
            }
        }
    }

    // ---- pack B: fp32 [d][o] -> LDS f16 [col][k], 8x8 in-register transpose ----
    {
        const int br = tid >> 4;         // d-block
        const int bc = tid & 15;         // o-block
        const float* src = Bsrc + (br * 8) * DIM + bc * 8;
        _Float16 m[8][8];
        #pragma unroll
        for (int u = 0; u < 8; ++u) {
            const float4 a = *(const float4*)(src + u * DIM);
            const float4 b = *(const float4*)(src + u * DIM + 4);
            m[u][0] = (_Float16)a.x; m[u][1] = (_Float16)a.y;
            m[u][2] = (_Float16)a.z; m[u][3] = (_Float16)a.w;
            m[u][4] = (_Float16)b.x; m[u][5] = (_Float16)b.y;
            m[u][6] = (_Float16)b.z; m[u][7] = (_Float16)b.w;
        }
        #pragma unroll
        for (int c2 = 0; c2 < 8; ++c2) {
            const int chunk = (bc * 8 + c2) * 16 + br;
            const int cs = chunk ^ (c2 & 7) ^ (bc & 7);
            f16x8 v = {m[0][c2], m[1][c2], m[2][c2], m[3][c2],
                       m[4][c2], m[5][c2], m[6][c2], m[7][c2]};
            *(f16x8*)(&Bl[cs * 8]) = v;
        }
    }
    __syncthreads();

    int nstrips;
    const int row0 = bid * 256;          // root rows (root blocks only)
    if (isEdge) {
        const int nr = min(lcnt, 128);   // uniform after barrier
        if (nr == 0) return;
        nstrips = (nr + 63) >> 6;        // 1 or 2
    } else {
        nstrips = 4;
    }

    const int l15 = lane & 15;
    const int q   = lane >> 4;
    _Float16* outb = isEdge ? msg_h : rootp_h;

    for (int s = 0; s < nstrips; ++s) {
        // A fragments: gather fp32 x row, cvt in-register (R9-R14 verified)
        const int ridx = s * 64 + w * 16 + l15;
        const int srcn = isEdge ? ssrc[ridx] : (row0 + ridx);
        const float* xrow = x + ((size_t)srcn << 7) + q * 8;
        f16x8 a[4];
        #pragma unroll
        for (int kb = 0; kb < 4; ++kb) {
            const float4 lo = *(const float4*)(xrow + kb * 32);
            const float4 hi = *(const float4*)(xrow + kb * 32 + 4);
            f16x8 av;
            av[0] = (_Float16)lo.x; av[1] = (_Float16)lo.y;
            av[2] = (_Float16)lo.z; av[3] = (_Float16)lo.w;
            av[4] = (_Float16)hi.x; av[5] = (_Float16)hi.y;
            av[6] = (_Float16)hi.z; av[7] = (_Float16)hi.w;
            a[kb] = av;
        }

        f32x4 acc[8];
        #pragma unroll
        for (int ct = 0; ct < 8; ++ct) acc[ct] = (f32x4){0.f, 0.f, 0.f, 0.f};

        #pragma unroll
        for (int ct = 0; ct < 8; ++ct) {
            const int col = ct * 16 + l15;
            const int sw  = (col & 7) ^ ((col >> 3) & 7);
            #pragma unroll
            for (int kb = 0; kb < 4; ++kb) {
                const int chunk = col * 16 + kb * 4 + q;
                const f16x8 bfr = *(const f16x8*)(&Bl[(chunk ^ sw) * 8]);
                acc[ct] = __builtin_amdgcn_mfma_f32_16x16x32_f16(a[kb], bfr, acc[ct], 0, 0, 0);
            }
        }

        #pragma unroll
        for (int j = 0; j < 4; ++j) {
            const int r = s * 64 + w * 16 + q * 4 + j;
            const int oid = isEdge ? soid[r] : (row0 + r);
            if (oid >= 0) {
                #pragma unroll
                for (int ct = 0; ct < 8; ++ct)
                    outb[((size_t)oid << 7) + ct * 16 + l15] = (_Float16)acc[ct][j];
            }
        }
    }
}

// ---------------- kernel 2: finalize, wave-per-graph (R14 verbatim) ----------------
__global__ __launch_bounds__(512) void finalize_kernel(
    const _Float16* __restrict__ rootp_h, const _Float16* __restrict__ msg_h,
    const float* __restrict__ bias, const float* __restrict__ target,
    const int* __restrict__ edge_index, float* __restrict__ out)
{
    const int g = blockIdx.x * 8 + (threadIdx.x >> 6);
    const int l = threadIdx.x & 63;
    const int d0 = l * 2;

    const float2 bv = *(const float2*)(bias + d0);
    float accA[NPG], accB[NPG];
    #pragma unroll
    for (int n = 0; n < NPG; ++n) {
        const _Float16* row = rootp_h + ((size_t)(g * NPG + n) << 7) + d0;
        accA[n] = bv.x + (float)row[0];
        accB[n] = bv.y + (float)row[1];
    }

    const int ebase = g * EPG;
    #pragma unroll
    for (int e = 0; e < EPG; ++e) {
        const int ge  = ebase + e;
        const int dst = edge_index[NUM_EDGES + ge] - g * NPG;
        const _Float16* mrow = msg_h + ((size_t)ge << 7) + d0;
        const float m0 = (float)mrow[0];
        const float m1 = (float)mrow[1];
        #pragma unroll
        for (int n = 0; n < NPG; ++n) {
            accA[n] += (n == dst) ? m0 : 0.f;
            accB[n] += (n == dst) ? m1 : 0.f;
        }
    }

    float p0 = 0.f, p1 = 0.f;
    #pragma unroll
    for (int n = 0; n < NPG; ++n) {
        p0 += fmaxf(accA[n], 0.f);
        p1 += fmaxf(accB[n], 0.f);
    }

    const float2 tv = *(const float2*)(target + (size_t)g * DIM + d0);
    float num_p = p0 * tv.x + p1 * tv.y;
    float na_p  = p0 * p0 + p1 * p1;
    float nb_p  = tv.x * tv.x + tv.y * tv.y;

    #pragma unroll
    for (int off = 32; off > 0; off >>= 1) {
        num_p += __shfl_down(num_p, off);
        na_p  += __shfl_down(na_p, off);
        nb_p  += __shfl_down(nb_p, off);
    }
    if (l == 0) {
        const float na = fmaxf(sqrtf(na_p), EPS);
        const float nb = fmaxf(sqrtf(nb_p), EPS);
        out[g] = num_p / (na * nb);
    }
}

// ---------------- fallback: verified fp32 single-kernel version (52.8 us) ----------------
__global__ __launch_bounds__(128) void rgcn_fused_kernel(
    const float* __restrict__ x, const float* __restrict__ basis,
    const float* __restrict__ root, const float* __restrict__ bias,
    const float* __restrict__ target, const int* __restrict__ edge_index,
    const int* __restrict__ edge_type, float* __restrict__ out)
{
    const int g = blockIdx.x;
    const int o = threadIdx.x;
    __shared__ float xs[NPG][DIM];
    __shared__ float red[6];
    {
        const float4* xg = reinterpret_cast<const float4*>(x + (size_t)g * NPG * DIM);
        float4* xs4 = reinterpret_cast<float4*>(&xs[0][0]);
        xs4[o] = xg[o];
        xs4[o + 128] = xg[o + 128];
    }
    __syncthreads();
    float acc[NPG];
    const float b = bias[o];
    #pragma unroll
    for (int n = 0; n < NPG; ++n) acc[n] = b;
    for (int d4 = 0; d4 < DIM / 4; ++d4) {
        const float r0 = root[(d4 * 4 + 0) * DIM + o];
        const float r1 = root[(d4 * 4 + 1) * DIM + o];
        const float r2 = root[(d4 * 4 + 2) * DIM + o];
        const float r3 = root[(d4 * 4 + 3) * DIM + o];
        #pragma unroll
        for (int n = 0; n < NPG; ++n) {
            const float4 xv = reinterpret_cast<const float4*>(&xs[n][0])[d4];
            acc[n] += xv.x * r0 + xv.y * r1 + xv.z * r2 + xv.w * r3;
        }
    }
    const int ebase = g * EPG;
    for (int e = 0; e < EPG; ++e) {
        const int ge  = ebase + e;
        const int src = edge_index[ge] - g * NPG;
        const int dst = edge_index[NUM_EDGES + ge] - g * NPG;
        const int rel = edge_type[ge];
        const float* __restrict__ B = basis + (size_t)rel * DIM * DIM;
        float m = 0.f;
        for (int d4 = 0; d4 < DIM / 4; ++d4) {
            const float4 xv = reinterpret_cast<const float4*>(&xs[src][0])[d4];
            m += xv.x * B[(d4 * 4 + 0) * DIM + o];
            m += xv.y * B[(d4 * 4 + 1) * DIM + o];
            m += xv.z * B[(d4 * 4 + 2) * DIM + o];
            m += xv.w * B[(d4 * 4 + 3) * DIM + o];
        }
        #pragma unroll
        for (int n = 0; n < NPG; ++n) acc[n] += (n == dst) ? m : 0.f;
    }
    float p = 0.f;
    #pragma unroll
    for (int n = 0; n < NPG; ++n) p += fmaxf(acc[n], 0.f);
    const float t = target[(size_t)g * DIM + o];
    float num_p = p * t, na_p = p * p, nb_p = t * t;
    #pragma unroll
    for (int off = 32; off > 0; off >>= 1) {
        num_p += __shfl_down(num_p, off);
        na_p  += __shfl_down(na_p, off);
        nb_p  += __shfl_down(nb_p, off);
    }
    const int wave = o >> 6, lane = o & 63;
    if (lane == 0) {
        red[wave * 3 + 0] = num_p;
        red[wave * 3 + 1] = na_p;
        red[wave * 3 + 2] = nb_p;
    }
    __syncthreads();
    if (o == 0) {
        const float num = red[0] + red[3];
        const float na  = fmaxf(sqrtf(red[1] + red[4]), EPS);
        const float nb  = fmaxf(sqrtf(red[2] + red[5]), EPS);
        out[g] = num / (na * nb);
    }
}

extern "C" void kernel_launch(void* const* d_in, const int* in_sizes, int n_in,
                              void* d_out, int out_size, void* d_ws, size_t ws_size,
                              hipStream_t stream) {
    const float* x          = (const float*)d_in[0];
    const float* basis      = (const float*)d_in[1];
    const float* root       = (const float*)d_in[2];
    const float* bias       = (const float*)d_in[3];
    const float* target     = (const float*)d_in[4];
    const int*   edge_index = (const int*)d_in[5];
    const int*   edge_type  = (const int*)d_in[6];
    float* out = (float*)d_out;

    if (ws_size < WS_NEEDED) {
        rgcn_fused_kernel<<<BATCH, 128, 0, stream>>>(
            x, basis, root, bias, target, edge_index, edge_type, out);
        return;
    }

    char* ws = (char*)d_ws;
    _Float16* msg_h   = (_Float16*)(ws + MSG_OFF);
    _Float16* rootp_h = (_Float16*)(ws + RTP_OFF);

    gemm2_kernel<<<ROOT_BLOCKS + EDGE_BLOCKS, 256, 0, stream>>>(
        x, basis, root, edge_index, edge_type, msg_h, rootp_h);
    finalize_kernel<<<BATCH / 8, 512, 0, stream>>>(
        rootp_h, msg_h, bias, target, edge_index, out);
}

// Round 17
// 24.373 us; speedup vs baseline: 1.5955x; 1.5466x over previous
//
#include <hip/hip_runtime.h>

#define NUM_NODES 16384
#define NPG 8
#define NUM_EDGES 14336
#define EPG 7
#define NUM_RELS 64
#define DIM 128
#define BATCH 2048
#define EPS 1e-8f

#define SEG 1792                     // NUM_EDGES / 8 segments
#define EDGE_BLOCKS 512              // kernel1: 64 rel x 8 segments, <=64 edges/cell (mean 28)
#define RF_BLOCKS 256                // kernel2: 64 node-rows + 8-graph finalize each

using f16x2 = __attribute__((ext_vector_type(2))) _Float16;
using f16x8 = __attribute__((ext_vector_type(8))) _Float16;
using f32x4 = __attribute__((ext_vector_type(4))) float;

// ---- ws layout (bytes) ----
#define MSG_OFF 0u                   // msg_h: 14336*128*2 = 3670016
#define WS_NEEDED 3670016u

// ---------------- kernel 1: edge bucket + pack + MFMA -> msg (R14-verified path) ----------------
// Block (rel=bid>>3, part=bid&7): LDS-atomic slot grab over its 1792-edge
// segment (slot order irrelevant -> deterministic output), pack B[rel]
// fp32->f16 transposed+swizzled into LDS, one 64-row MFMA strip.
// Swizzle cs = chunk^(col&7)^((col>>3)&7): conflict-free stores AND reads.
__global__ __launch_bounds__(256, 4) void edge_gemm_kernel(
    const float* __restrict__ x, const float* __restrict__ basis,
    const int* __restrict__ edge_index, const int* __restrict__ edge_type,
    _Float16* __restrict__ msg_h)
{
    __shared__ _Float16 Bl[DIM * DIM];   // 32 KB
    __shared__ int smeta[128];           // [0:64) src node, [64:128) out row id (-1 = skip)
    __shared__ int lcnt;

    const int bid = blockIdx.x;
    const int tid = threadIdx.x;
    const int lane = tid & 63;
    const int w    = tid >> 6;
    const int rel  = bid >> 3;

    if (tid < 64) { smeta[tid] = 0; smeta[64 + tid] = -1; }
    if (tid == 0) lcnt = 0;
    __syncthreads();

    // scan (no barriers; interleaves with pack)
    {
        const int seg0 = (bid & 7) * SEG;
        #pragma unroll
        for (int it = 0; it < 7; ++it) {
            const int e = seg0 + it * 256 + tid;
            if (edge_type[e] == rel) {
                const int pos = atomicAdd(&lcnt, 1);
                if (pos < 64) {
                    smeta[pos] = edge_index[e];
                    smeta[64 + pos] = e;
                }
            }
        }
    }

    // pack B[rel]: fp32 [d][o] -> LDS f16 [col][k], 8x8 in-register transpose
    {
        const int br = tid >> 4;
        const int bc = tid & 15;
        const float* src = basis + ((size_t)rel << 14) + (br * 8) * DIM + bc * 8;
        _Float16 m[8][8];
        #pragma unroll
        for (int u = 0; u < 8; ++u) {
            const float4 a = *(const float4*)(src + u * DIM);
            const float4 b = *(const float4*)(src + u * DIM + 4);
            m[u][0] = (_Float16)a.x; m[u][1] = (_Float16)a.y;
            m[u][2] = (_Float16)a.z; m[u][3] = (_Float16)a.w;
            m[u][4] = (_Float16)b.x; m[u][5] = (_Float16)b.y;
            m[u][6] = (_Float16)b.z; m[u][7] = (_Float16)b.w;
        }
        #pragma unroll
        for (int c2 = 0; c2 < 8; ++c2) {
            const int chunk = (bc * 8 + c2) * 16 + br;
            const int cs = chunk ^ (c2 & 7) ^ (bc & 7);
            f16x8 v = {m[0][c2], m[1][c2], m[2][c2], m[3][c2],
                       m[4][c2], m[5][c2], m[6][c2], m[7][c2]};
            *(f16x8*)(&Bl[cs * 8]) = v;
        }
    }
    __syncthreads();

    if (lcnt == 0) return;               // block-uniform

    const int l15 = lane & 15;
    const int q   = lane >> 4;

    const int srcn = smeta[w * 16 + l15];
    const float* xrow = x + ((size_t)srcn << 7) + q * 8;
    f16x8 a[4];
    #pragma unroll
    for (int kb = 0; kb < 4; ++kb) {
        const float4 lo = *(const float4*)(xrow + kb * 32);
        const float4 hi = *(const float4*)(xrow + kb * 32 + 4);
        f16x8 av;
        av[0] = (_Float16)lo.x; av[1] = (_Float16)lo.y;
        av[2] = (_Float16)lo.z; av[3] = (_Float16)lo.w;
        av[4] = (_Float16)hi.x; av[5] = (_Float16)hi.y;
        av[6] = (_Float16)hi.z; av[7] = (_Float16)hi.w;
        a[kb] = av;
    }

    f32x4 acc[8];
    #pragma unroll
    for (int ct = 0; ct < 8; ++ct) acc[ct] = (f32x4){0.f, 0.f, 0.f, 0.f};

    #pragma unroll
    for (int ct = 0; ct < 8; ++ct) {
        const int col = ct * 16 + l15;
        const int sw  = (col & 7) ^ ((col >> 3) & 7);
        #pragma unroll
        for (int kb = 0; kb < 4; ++kb) {
            const int chunk = col * 16 + kb * 4 + q;
            const f16x8 bfr = *(const f16x8*)(&Bl[(chunk ^ sw) * 8]);
            acc[ct] = __builtin_amdgcn_mfma_f32_16x16x32_f16(a[kb], bfr, acc[ct], 0, 0, 0);
        }
    }

    #pragma unroll
    for (int j = 0; j < 4; ++j) {
        const int r = w * 16 + q * 4 + j;
        const int oid = smeta[64 + r];
        if (oid >= 0) {
            #pragma unroll
            for (int ct = 0; ct < 8; ++ct)
                msg_h[((size_t)oid << 7) + ct * 16 + l15] = (_Float16)acc[ct][j];
        }
    }
}

// ---------------- kernel 2: root GEMM (C->LDS) + finalize (R15-verified path, no flags) ----------------
// Block rb: node rows rb*64..+63 = graphs rb*8..+7. Pack root once, MFMA,
// C-tile -> LDS [64][132] f16 (conflict-free), then per-wave finalize of 2 graphs.
// msg_h visibility guaranteed by the kernel boundary.
__global__ __launch_bounds__(256, 4) void root_finalize_kernel(
    const float* __restrict__ x, const float* __restrict__ root,
    const float* __restrict__ bias, const float* __restrict__ target,
    const int* __restrict__ edge_index, const _Float16* __restrict__ msg_h,
    float* __restrict__ out)
{
    __shared__ _Float16 Bl[DIM * DIM];   // 32 KB; reused as C-tile after MFMA

    const int rb  = blockIdx.x;
    const int tid = threadIdx.x;
    const int lane = tid & 63;
    const int w    = tid >> 6;
    const int row0 = rb * 64;

    // pack root: fp32 [d][o] -> LDS f16 [col][k]
    {
        const int br = tid >> 4;
        const int bc = tid & 15;
        const float* src = root + (br * 8) * DIM + bc * 8;
        _Float16 m[8][8];
        #pragma unroll
        for (int u = 0; u < 8; ++u) {
            const float4 a = *(const float4*)(src + u * DIM);
            const float4 b = *(const float4*)(src + u * DIM + 4);
            m[u][0] = (_Float16)a.x; m[u][1] = (_Float16)a.y;
            m[u][2] = (_Float16)a.z; m[u][3] = (_Float16)a.w;
            m[u][4] = (_Float16)b.x; m[u][5] = (_Float16)b.y;
            m[u][6] = (_Float16)b.z; m[u][7] = (_Float16)b.w;
        }
        #pragma unroll
        for (int c2 = 0; c2 < 8; ++c2) {
            const int chunk = (bc * 8 + c2) * 16 + br;
            const int cs = chunk ^ (c2 & 7) ^ (bc & 7);
            f16x8 v = {m[0][c2], m[1][c2], m[2][c2], m[3][c2],
                       m[4][c2], m[5][c2], m[6][c2], m[7][c2]};
            *(f16x8*)(&Bl[cs * 8]) = v;
        }
    }
    __syncthreads();

    const int l15 = lane & 15;
    const int q   = lane >> 4;

    const float* xrow = x + ((size_t)(row0 + w * 16 + l15) << 7) + q * 8;
    f16x8 a[4];
    #pragma unroll
    for (int kb = 0; kb < 4; ++kb) {
        const float4 lo = *(const float4*)(xrow + kb * 32);
        const float4 hi = *(const float4*)(xrow + kb * 32 + 4);
        f16x8 av;
        av[0] = (_Float16)lo.x; av[1] = (_Float16)lo.y;
        av[2] = (_Float16)lo.z; av[3] = (_Float16)lo.w;
        av[4] = (_Float16)hi.x; av[5] = (_Float16)hi.y;
        av[6] = (_Float16)hi.z; av[7] = (_Float16)hi.w;
        a[kb] = av;
    }

    f32x4 acc[8];
    #pragma unroll
    for (int ct = 0; ct < 8; ++ct) acc[ct] = (f32x4){0.f, 0.f, 0.f, 0.f};

    #pragma unroll
    for (int ct = 0; ct < 8; ++ct) {
        const int col = ct * 16 + l15;
        const int sw  = (col & 7) ^ ((col >> 3) & 7);
        #pragma unroll
        for (int kb = 0; kb < 4; ++kb) {
            const int chunk = col * 16 + kb * 4 + q;
            const f16x8 bfr = *(const f16x8*)(&Bl[(chunk ^ sw) * 8]);
            acc[ct] = __builtin_amdgcn_mfma_f32_16x16x32_f16(a[kb], bfr, acc[ct], 0, 0, 0);
        }
    }

    __syncthreads();                     // B-fragment reads done before Bl reuse
    _Float16* Cl = Bl;                   // [64][132] f16 (stride 132: conflict-free)
    #pragma unroll
    for (int j = 0; j < 4; ++j) {
        const int lr = w * 16 + q * 4 + j;
        #pragma unroll
        for (int ct = 0; ct < 8; ++ct)
            Cl[lr * 132 + ct * 16 + l15] = (_Float16)acc[ct][j];
    }
    __syncthreads();

    // finalize: wave w handles graphs rb*8 + w*2 + {0,1}  (R15-verified)
    #pragma unroll
    for (int k = 0; k < 2; ++k) {
        const int lg = w * 2 + k;
        const int g  = rb * 8 + lg;
        const int d0 = lane * 2;

        const float2 bv = *(const float2*)(bias + d0);
        float accA[NPG], accB[NPG];
        #pragma unroll
        for (int n = 0; n < NPG; ++n) {
            const f16x2 c = *(const f16x2*)(&Cl[(lg * 8 + n) * 132 + d0]);
            accA[n] = bv.x + (float)c[0];
            accB[n] = bv.y + (float)c[1];
        }

        const int ebase = g * EPG;
        #pragma unroll
        for (int e = 0; e < EPG; ++e) {
            const int ge  = ebase + e;
            const int dst = edge_index[NUM_EDGES + ge] - g * NPG;
            const f16x2 mv = *(const f16x2*)(msg_h + ((size_t)ge << 7) + d0);
            const float m0 = (float)mv[0];
            const float m1 = (float)mv[1];
            #pragma unroll
            for (int n = 0; n < NPG; ++n) {
                accA[n] += (n == dst) ? m0 : 0.f;
                accB[n] += (n == dst) ? m1 : 0.f;
            }
        }

        float p0 = 0.f, p1 = 0.f;
        #pragma unroll
        for (int n = 0; n < NPG; ++n) {
            p0 += fmaxf(accA[n], 0.f);
            p1 += fmaxf(accB[n], 0.f);
        }

        const float2 tv = *(const float2*)(target + (size_t)g * DIM + d0);
        float num_p = p0 * tv.x + p1 * tv.y;
        float na_p  = p0 * p0 + p1 * p1;
        float nb_p  = tv.x * tv.x + tv.y * tv.y;

        #pragma unroll
        for (int off = 32; off > 0; off >>= 1) {
            num_p += __shfl_down(num_p, off);
            na_p  += __shfl_down(na_p, off);
            nb_p  += __shfl_down(nb_p, off);
        }
        if (lane == 0) {
            const float na = fmaxf(sqrtf(na_p), EPS);
            const float nb = fmaxf(sqrtf(nb_p), EPS);
            out[g] = num_p / (na * nb);
        }
    }
}

// ---------------- fallback: verified fp32 single-kernel version (52.8 us) ----------------
__global__ __launch_bounds__(128) void rgcn_fused_kernel(
    const float* __restrict__ x, const float* __restrict__ basis,
    const float* __restrict__ root, const float* __restrict__ bias,
    const float* __restrict__ target, const int* __restrict__ edge_index,
    const int* __restrict__ edge_type, float* __restrict__ out)
{
    const int g = blockIdx.x;
    const int o = threadIdx.x;
    __shared__ float xs[NPG][DIM];
    __shared__ float red[6];
    {
        const float4* xg = reinterpret_cast<const float4*>(x + (size_t)g * NPG * DIM);
        float4* xs4 = reinterpret_cast<float4*>(&xs[0][0]);
        xs4[o] = xg[o];
        xs4[o + 128] = xg[o + 128];
    }
    __syncthreads();
    float acc[NPG];
    const float b = bias[o];
    #pragma unroll
    for (int n = 0; n < NPG; ++n) acc[n] = b;
    for (int d4 = 0; d4 < DIM / 4; ++d4) {
        const float r0 = root[(d4 * 4 + 0) * DIM + o];
        const float r1 = root[(d4 * 4 + 1) * DIM + o];
        const float r2 = root[(d4 * 4 + 2) * DIM + o];
        const float r3 = root[(d4 * 4 + 3) * DIM + o];
        #pragma unroll
        for (int n = 0; n < NPG; ++n) {
            const float4 xv = reinterpret_cast<const float4*>(&xs[n][0])[d4];
            acc[n] += xv.x * r0 + xv.y * r1 + xv.z * r2 + xv.w * r3;
        }
    }
    const int ebase = g * EPG;
    for (int e = 0; e < EPG; ++e) {
        const int ge  = ebase + e;
        const int src = edge_index[ge] - g * NPG;
        const int dst = edge_index[NUM_EDGES + ge] - g * NPG;
        const int rel = edge_type[ge];
        const float* __restrict__ B = basis + (size_t)rel * DIM * DIM;
        float m = 0.f;
        for (int d4 = 0; d4 < DIM / 4; ++d4) {
            const float4 xv = reinterpret_cast<const float4*>(&xs[src][0])[d4];
            m += xv.x * B[(d4 * 4 + 0) * DIM + o];
            m += xv.y * B[(d4 * 4 + 1) * DIM + o];
            m += xv.z * B[(d4 * 4 + 2) * DIM + o];
            m += xv.w * B[(d4 * 4 + 3) * DIM + o];
        }
        #pragma unroll
        for (int n = 0; n < NPG; ++n) acc[n] += (n == dst) ? m : 0.f;
    }
    float p = 0.f;
    #pragma unroll
    for (int n = 0; n < NPG; ++n) p += fmaxf(acc[n], 0.f);
    const float t = target[(size_t)g * DIM + o];
    float num_p = p * t, na_p = p * p, nb_p = t * t;
    #pragma unroll
    for (int off = 32; off > 0; off >>= 1) {
        num_p += __shfl_down(num_p, off);
        na_p  += __shfl_down(na_p, off);
        nb_p  += __shfl_down(nb_p, off);
    }
    const int wave = o >> 6, lane = o & 63;
    if (lane == 0) {
        red[wave * 3 + 0] = num_p;
        red[wave * 3 + 1] = na_p;
        red[wave * 3 + 2] = nb_p;
    }
    __syncthreads();
    if (o == 0) {
        const float num = red[0] + red[3];
        const float na  = fmaxf(sqrtf(red[1] + red[4]), EPS);
        const float nb  = fmaxf(sqrtf(red[2] + red[5]), EPS);
        out[g] = num / (na * nb);
    }
}

extern "C" void kernel_launch(void* const* d_in, const int* in_sizes, int n_in,
                              void* d_out, int out_size, void* d_ws, size_t ws_size,
                              hipStream_t stream) {
    const float* x          = (const float*)d_in[0];
    const float* basis      = (const float*)d_in[1];
    const float* root       = (const float*)d_in[2];
    const float* bias       = (const float*)d_in[3];
    const float* target     = (const float*)d_in[4];
    const int*   edge_index = (const int*)d_in[5];
    const int*   edge_type  = (const int*)d_in[6];
    float* out = (float*)d_out;

    if (ws_size < WS_NEEDED) {
        rgcn_fused_kernel<<<BATCH, 128, 0, stream>>>(
            x, basis, root, bias, target, edge_index, edge_type, out);
        return;
    }

    _Float16* msg_h = (_Float16*)((char*)d_ws + MSG_OFF);

    edge_gemm_kernel<<<EDGE_BLOCKS, 256, 0, stream>>>(
        x, basis, edge_index, edge_type, msg_h);
    root_finalize_kernel<<<RF_BLOCKS, 256, 0, stream>>>(
        x, root, bias, target, edge_index, msg_h, out);
}

// Round 18
// 22.255 us; speedup vs baseline: 1.7474x; 1.0952x over previous
//
#include <hip/hip_runtime.h>

#define NUM_NODES 16384
#define NPG 8
#define NUM_EDGES 14336
#define EPG 7
#define NUM_RELS 64
#define DIM 128
#define BATCH 2048
#define EPS 1e-8f

#define SEG 1792                     // NUM_EDGES / 8 segments
#define ROOT_BLOCKS 256              // 16384 / 64, dispatched FIRST (uniform tail)
#define EDGE_BLOCKS 512              // 64 rel x 8 segments, <=64 edges each (avg 28)

using f16x8 = __attribute__((ext_vector_type(8))) _Float16;
using f32x4 = __attribute__((ext_vector_type(4))) float;

// ---- ws layout (bytes) ----
#define MSG_OFF 0u                   // msg_h: 14336*128*2 = 3670016
#define RTP_OFF 3670016u             // rootp: 16384*128*2 = 4194304
#define WS_NEEDED 7864320u

// ---------------- kernel 1: fused bucket + pack + MFMA GEMM (R14, 22.25us verified) ----------------
// Root block (bid<256): rows bid*64..+63 with root matrix — runs CONCURRENTLY
// with edge blocks (R17 lesson: serializing root behind a launch boundary costs
// more than the rootp round-trip saves; latency-bound workload -> parallelism wins).
// Edge block: LDS-atomic slot grab over its 1792-edge segment (slot order
// irrelevant: msg rows keyed by absolute edge id -> deterministic), pack B[rel]
// fp32->f16 transposed into LDS, one 64-row MFMA strip. 2 barriers total.
// LDS: 16B chunks, chunk = col*16+k16, swizzle cs = chunk^(col&7)^((col>>3)&7)
// -> conflict-free on both transpose stores and fragment reads.
__global__ __launch_bounds__(256) void gemm2_kernel(
    const float* __restrict__ x, const float* __restrict__ basis,
    const float* __restrict__ root, const int* __restrict__ edge_index,
    const int* __restrict__ edge_type,
    _Float16* __restrict__ msg_h, _Float16* __restrict__ rootp_h)
{
    __shared__ _Float16 Bl[DIM * DIM];   // 32 KB
    __shared__ int smeta[128];           // [0:64) src node, [64:128) out row id (-1 = skip)
    __shared__ int lcnt;

    const int bid = blockIdx.x;
    const int tid = threadIdx.x;
    const int lane = tid & 63;
    const int w    = tid >> 6;
    const bool isEdge = bid >= ROOT_BLOCKS;

    const float* Bsrc;

    // ---- init LDS metadata ----
    if (isEdge) {
        if (tid < 64) { smeta[tid] = 0; smeta[64 + tid] = -1; }
        if (tid == 0) lcnt = 0;
        Bsrc = basis + ((size_t)((bid - ROOT_BLOCKS) >> 3) << 14);
    } else {
        const int row0 = bid * 64;
        if (tid < 64) {
            smeta[tid] = row0 + tid;
            smeta[64 + tid] = row0 + tid;
        }
        Bsrc = root;
    }
    __syncthreads();

    // ---- scan (edge blocks only; no barriers) ----
    if (isEdge) {
        const int eb   = bid - ROOT_BLOCKS;
        const int rel  = eb >> 3;
        const int seg0 = (eb & 7) * SEG;
        #pragma unroll
        for (int it = 0; it < 7; ++it) {
            const int e = seg0 + it * 256 + tid;
            if (edge_type[e] == rel) {
                const int pos = atomicAdd(&lcnt, 1);
                if (pos < 64) {
                    smeta[pos] = edge_index[e];      // global src node
                    smeta[64 + pos] = e;             // msg row id
                }
            }
        }
    }

    // ---- pack B: fp32 [d][o] -> LDS f16 [col][k], 8x8 in-register transpose ----
    // (independent of scan; interleaves with it)
    {
        const int br = tid >> 4;         // d-block (k16 = br)
        const int bc = tid & 15;         // o-block
        const float* src = Bsrc + (br * 8) * DIM + bc * 8;
        _Float16 m[8][8];
        #pragma unroll
        for (int u = 0; u < 8; ++u) {
            const float4 a = *(const float4*)(src + u * DIM);
            const float4 b = *(const float4*)(src + u * DIM + 4);
            m[u][0] = (_Float16)a.x; m[u][1] = (_Float16)a.y;
            m[u][2] = (_Float16)a.z; m[u][3] = (_Float16)a.w;
            m[u][4] = (_Float16)b.x; m[u][5] = (_Float16)b.y;
            m[u][6] = (_Float16)b.z; m[u][7] = (_Float16)b.w;
        }
        #pragma unroll
        for (int c2 = 0; c2 < 8; ++c2) {
            const int col = bc * 8 + c2;
            const int chunk = col * 16 + br;
            const int cs = chunk ^ (c2 & 7) ^ (bc & 7);   // == chunk^(col&7)^((col>>3)&7)
            f16x8 v = {m[0][c2], m[1][c2], m[2][c2], m[3][c2],
                       m[4][c2], m[5][c2], m[6][c2], m[7][c2]};
            *(f16x8*)(&Bl[cs * 8]) = v;
        }
    }
    __syncthreads();

    if (isEdge && lcnt == 0) return;     // block-uniform (safety only)

    const int l15 = lane & 15;
    const int q   = lane >> 4;

    // A fragments: gather fp32 x row, convert in-register (verified R9-R14)
    const int src = smeta[w * 16 + l15];
    const float* xrow = x + ((size_t)src << 7) + q * 8;
    f16x8 a[4];
    #pragma unroll
    for (int kb = 0; kb < 4; ++kb) {
        const float4 lo = *(const float4*)(xrow + kb * 32);
        const float4 hi = *(const float4*)(xrow + kb * 32 + 4);
        f16x8 av;
        av[0] = (_Float16)lo.x; av[1] = (_Float16)lo.y;
        av[2] = (_Float16)lo.z; av[3] = (_Float16)lo.w;
        av[4] = (_Float16)hi.x; av[5] = (_Float16)hi.y;
        av[6] = (_Float16)hi.z; av[7] = (_Float16)hi.w;
        a[kb] = av;
    }

    f32x4 acc[8];
    #pragma unroll
    for (int ct = 0; ct < 8; ++ct) acc[ct] = (f32x4){0.f, 0.f, 0.f, 0.f};

    #pragma unroll
    for (int ct = 0; ct < 8; ++ct) {
        const int col = ct * 16 + l15;
        const int sw  = (col & 7) ^ ((col >> 3) & 7);
        #pragma unroll
        for (int kb = 0; kb < 4; ++kb) {
            const int chunk = col * 16 + kb * 4 + q;
            const int cs = chunk ^ sw;
            const f16x8 bfr = *(const f16x8*)(&Bl[cs * 8]);
            acc[ct] = __builtin_amdgcn_mfma_f32_16x16x32_f16(a[kb], bfr, acc[ct], 0, 0, 0);
        }
    }

    _Float16* outb = isEdge ? msg_h : rootp_h;
    #pragma unroll
    for (int j = 0; j < 4; ++j) {
        const int r = w * 16 + q * 4 + j;
        const int oid = smeta[64 + r];
        if (oid >= 0) {
            #pragma unroll
            for (int ct = 0; ct < 8; ++ct) {
                outb[((size_t)oid << 7) + ct * 16 + l15] = (_Float16)acc[ct][j];
            }
        }
    }
}

// ---------------- kernel 2: finalize, wave-per-graph (512-thread blocks, R14 verified) ----------------
__global__ __launch_bounds__(512) void finalize_kernel(
    const _Float16* __restrict__ rootp_h, const _Float16* __restrict__ msg_h,
    const float* __restrict__ bias, const float* __restrict__ target,
    const int* __restrict__ edge_index, float* __restrict__ out)
{
    const int g = blockIdx.x * 8 + (threadIdx.x >> 6);
    const int l = threadIdx.x & 63;
    const int d0 = l * 2;

    const float2 bv = *(const float2*)(bias + d0);
    float accA[NPG], accB[NPG];
    #pragma unroll
    for (int n = 0; n < NPG; ++n) {
        const _Float16* row = rootp_h + ((size_t)(g * NPG + n) << 7) + d0;
        accA[n] = bv.x + (float)row[0];
        accB[n] = bv.y + (float)row[1];
    }

    const int ebase = g * EPG;
    #pragma unroll
    for (int e = 0; e < EPG; ++e) {
        const int ge  = ebase + e;
        const int dst = edge_index[NUM_EDGES + ge] - g * NPG;
        const _Float16* mrow = msg_h + ((size_t)ge << 7) + d0;
        const float m0 = (float)mrow[0];
        const float m1 = (float)mrow[1];
        #pragma unroll
        for (int n = 0; n < NPG; ++n) {
            accA[n] += (n == dst) ? m0 : 0.f;
            accB[n] += (n == dst) ? m1 : 0.f;
        }
    }

    float p0 = 0.f, p1 = 0.f;
    #pragma unroll
    for (int n = 0; n < NPG; ++n) {
        p0 += fmaxf(accA[n], 0.f);
        p1 += fmaxf(accB[n], 0.f);
    }

    const float2 tv = *(const float2*)(target + (size_t)g * DIM + d0);
    float num_p = p0 * tv.x + p1 * tv.y;
    float na_p  = p0 * p0 + p1 * p1;
    float nb_p  = tv.x * tv.x + tv.y * tv.y;

    #pragma unroll
    for (int off = 32; off > 0; off >>= 1) {
        num_p += __shfl_down(num_p, off);
        na_p  += __shfl_down(na_p, off);
        nb_p  += __shfl_down(nb_p, off);
    }
    if (l == 0) {
        const float na = fmaxf(sqrtf(na_p), EPS);
        const float nb = fmaxf(sqrtf(nb_p), EPS);
        out[g] = num_p / (na * nb);
    }
}

// ---------------- fallback: verified fp32 single-kernel version (52.8 us) ----------------
__global__ __launch_bounds__(128) void rgcn_fused_kernel(
    const float* __restrict__ x, const float* __restrict__ basis,
    const float* __restrict__ root, const float* __restrict__ bias,
    const float* __restrict__ target, const int* __restrict__ edge_index,
    const int* __restrict__ edge_type, float* __restrict__ out)
{
    const int g = blockIdx.x;
    const int o = threadIdx.x;
    __shared__ float xs[NPG][DIM];
    __shared__ float red[6];
    {
        const float4* xg = reinterpret_cast<const float4*>(x + (size_t)g * NPG * DIM);
        float4* xs4 = reinterpret_cast<float4*>(&xs[0][0]);
        xs4[o] = xg[o];
        xs4[o + 128] = xg[o + 128];
    }
    __syncthreads();
    float acc[NPG];
    const float b = bias[o];
    #pragma unroll
    for (int n = 0; n < NPG; ++n) acc[n] = b;
    for (int d4 = 0; d4 < DIM / 4; ++d4) {
        const float r0 = root[(d4 * 4 + 0) * DIM + o];
        const float r1 = root[(d4 * 4 + 1) * DIM + o];
        const float r2 = root[(d4 * 4 + 2) * DIM + o];
        const float r3 = root[(d4 * 4 + 3) * DIM + o];
        #pragma unroll
        for (int n = 0; n < NPG; ++n) {
            const float4 xv = reinterpret_cast<const float4*>(&xs[n][0])[d4];
            acc[n] += xv.x * r0 + xv.y * r1 + xv.z * r2 + xv.w * r3;
        }
    }
    const int ebase = g * EPG;
    for (int e = 0; e < EPG; ++e) {
        const int ge  = ebase + e;
        const int src = edge_index[ge] - g * NPG;
        const int dst = edge_index[NUM_EDGES + ge] - g * NPG;
        const int rel = edge_type[ge];
        const float* __restrict__ B = basis + (size_t)rel * DIM * DIM;
        float m = 0.f;
        for (int d4 = 0; d4 < DIM / 4; ++d4) {
            const float4 xv = reinterpret_cast<const float4*>(&xs[src][0])[d4];
            m += xv.x * B[(d4 * 4 + 0) * DIM + o];
            m += xv.y * B[(d4 * 4 + 1) * DIM + o];
            m += xv.z * B[(d4 * 4 + 2) * DIM + o];
            m += xv.w * B[(d4 * 4 + 3) * DIM + o];
        }
        #pragma unroll
        for (int n = 0; n < NPG; ++n) acc[n] += (n == dst) ? m : 0.f;
    }
    float p = 0.f;
    #pragma unroll
    for (int n = 0; n < NPG; ++n) p += fmaxf(acc[n], 0.f);
    const float t = target[(size_t)g * DIM + o];
    float num_p = p * t, na_p = p * p, nb_p = t * t;
    #pragma unroll
    for (int off = 32; off > 0; off >>= 1) {
        num_p += __shfl_down(num_p, off);
        na_p  += __shfl_down(na_p, off);
        nb_p  += __shfl_down(nb_p, off);
    }
    const int wave = o >> 6, lane = o & 63;
    if (lane == 0) {
        red[wave * 3 + 0] = num_p;
        red[wave * 3 + 1] = na_p;
        red[wave * 3 + 2] = nb_p;
    }
    __syncthreads();
    if (o == 0) {
        const float num = red[0] + red[3];
        const float na  = fmaxf(sqrtf(red[1] + red[4]), EPS);
        const float nb  = fmaxf(sqrtf(red[2] + red[5]), EPS);
        out[g] = num / (na * nb);
    }
}

extern "C" void kernel_launch(void* const* d_in, const int* in_sizes, int n_in,
                              void* d_out, int out_size, void* d_ws, size_t ws_size,
                              hipStream_t stream) {
    const float* x          = (const float*)d_in[0];
    const float* basis      = (const float*)d_in[1];
    const float* root       = (const float*)d_in[2];
    const float* bias       = (const float*)d_in[3];
    const float* target     = (const float*)d_in[4];
    const int*   edge_index = (const int*)d_in[5];
    const int*   edge_type  = (const int*)d_in[6];
    float* out = (float*)d_out;

    if (ws_size < WS_NEEDED) {
        rgcn_fused_kernel<<<BATCH, 128, 0, stream>>>(
            x, basis, root, bias, target, edge_index, edge_type, out);
        return;
    }

    char* ws = (char*)d_ws;
    _Float16* msg_h   = (_Float16*)(ws + MSG_OFF);
    _Float16* rootp_h = (_Float16*)(ws + RTP_OFF);

    gemm2_kernel<<<ROOT_BLOCKS + EDGE_BLOCKS, 256, 0, stream>>>(
        x, basis, root, edge_index, edge_type, msg_h, rootp_h);
    finalize_kernel<<<BATCH / 8, 512, 0, stream>>>(
        rootp_h, msg_h, bias, target, edge_index, out);
}